// Round 23
// baseline (57.451 us; speedup 1.0000x reference)
//
#include <hip/hip_runtime.h>
#include <hip/hip_bf16.h>
#include <math.h>

#define NN 8
#define CC 256
#define LL 8192
#define KK 3
#define GG 8
#define GCC 32
#define OMD 48  // 2*G*K
#define TL 32   // k1 positions per block
#define FT 64   // fused-kernel positions per block

typedef __attribute__((ext_vector_type(8))) short short8v;   // 8 bf16 (4 VGPR)
typedef __attribute__((ext_vector_type(4))) float floatx4;

__device__ inline ushort f2bf(float f) {
    uint u = __float_as_uint(f);
    u += 0x7fffu + ((u >> 16) & 1u);   // RNE
    return (ushort)(u >> 16);
}

// branch-free GELU (tanh form) via hardware exp: max |err vs exact| ~3e-3
__device__ inline float gelu_fast(float xn) {
    float u = xn * xn;
    float z = xn * (-1.5957691216f - 0.0713548162726f * u);
    return __fdividef(xn, 1.f + __expf(z));
}

// ---------------- kernel 1: LN + GELU -> xa bf16 [N,L,C] ----------------------
// (r20-identical)
__global__ __launch_bounds__(256, 6) void k_ln_gelu(
    const float* __restrict__ x,
    const float* __restrict__ ln_w, const float* __restrict__ ln_b,
    __hip_bfloat16* __restrict__ xa)
{
    __shared__ __align__(16) float xs[128 * 33];   // 16896 B (= 1056 uint4)
    int n  = blockIdx.y;
    int l0 = blockIdx.x * TL;
    int t  = threadIdx.x;
    int p   = t >> 3;        // position 0..31
    int sub = t & 7;         // channel chunk 0..7
    int pp  = p ^ (sub << 2);

    const float* xbase = x + (size_t)n * CC * LL + l0;
    float r[32];

    float4 v[8];
    #pragma unroll
    for (int it = 0; it < 8; ++it) {
        int idx = it * 256 + t;
        int c   = idx >> 3;
        int l4  = idx & 7;
        v[it] = *reinterpret_cast<const float4*>(xbase + (size_t)c * LL + l4 * 4);
    }

    #pragma unroll
    for (int half = 0; half < 2; ++half) {
        if (half) __syncthreads();
        #pragma unroll
        for (int it = 0; it < 4; ++it) {
            int idx = (half * 4 + it) * 256 + t;
            int cl  = (idx >> 3) & 127;
            int l4  = idx & 7;
            int sw  = (cl >> 4) << 2;
            int b   = cl * 33;
            float4 vv = v[half * 4 + it];
            xs[b + ((4 * l4 + 0) ^ sw)] = vv.x;
            xs[b + ((4 * l4 + 1) ^ sw)] = vv.y;
            xs[b + ((4 * l4 + 2) ^ sw)] = vv.z;
            xs[b + ((4 * l4 + 3) ^ sw)] = vv.w;
        }
        __syncthreads();
        #pragma unroll
        for (int j = 0; j < 16; ++j)
            r[half * 16 + j] = xs[(sub * 16 + j) * 33 + pp];
    }

    float sum = 0.f, sq = 0.f;
    #pragma unroll
    for (int j = 0; j < 32; ++j) { sum += r[j]; sq = fmaf(r[j], r[j], sq); }
    #pragma unroll
    for (int m = 1; m <= 4; m <<= 1) {
        sum += __shfl_xor(sum, m);
        sq  += __shfl_xor(sq, m);
    }
    float mean = sum * (1.f / 256.f);
    float rstd = rsqrtf(sq * (1.f / 256.f) - mean * mean + 1e-6f);

    __syncthreads();   // all park-reads done; xs becomes the bf16 tile
    uint4* xb4 = reinterpret_cast<uint4*>(xs);   // [32 rows][33 uint4 pitch]

    #pragma unroll
    for (int half = 0; half < 2; ++half) {
        int cb = half * 128 + sub * 16;
        ushort pk[16];
        #pragma unroll
        for (int q = 0; q < 4; ++q) {
            float4 lw = *reinterpret_cast<const float4*>(ln_w + cb + 4 * q);
            float4 lb = *reinterpret_cast<const float4*>(ln_b + cb + 4 * q);
            float lww[4] = {lw.x, lw.y, lw.z, lw.w};
            float lbb[4] = {lb.x, lb.y, lb.z, lb.w};
            #pragma unroll
            for (int i = 0; i < 4; ++i) {
                int j = 4 * q + i;
                float xn = (r[half * 16 + j] - mean) * rstd * lww[i] + lbb[i];
                pk[j] = f2bf(gelu_fast(xn));
            }
        }
        #pragma unroll
        for (int q = 0; q < 2; ++q) {
            uint4 w4;
            w4.x = (uint)pk[8*q+0] | ((uint)pk[8*q+1] << 16);
            w4.y = (uint)pk[8*q+2] | ((uint)pk[8*q+3] << 16);
            w4.z = (uint)pk[8*q+4] | ((uint)pk[8*q+5] << 16);
            w4.w = (uint)pk[8*q+6] | ((uint)pk[8*q+7] << 16);
            xb4[p * 33 + (cb >> 3) + q] = w4;
        }
    }
    __syncthreads();

    // dense store: 1024 uint4, 4 per thread; each wave = 2 x 512 B contiguous
    #pragma unroll
    for (int it = 0; it < 4; ++it) {
        int idx = it * 256 + t;
        int row = idx >> 5;        // position 0..31
        int col = idx & 31;        // uint4 column
        uint4* dst = reinterpret_cast<uint4*>(xa + ((size_t)n * LL + l0 + row) * CC);
        dst[col] = xb4[row * 33 + col];
    }
}

// -------- kernel 2 (fused): om via MFMA -> LDS, then gather + aggregate -------
// Group-split: blockIdx.z = h selects groups 4h..4h+3. om_s holds only the 24
// columns this half needs (12 off + 12 mask) -> LDS 31.0 KB -> 5 blocks/CU.
// MFMA computes all 48 cols (cheap); predicate-stores the needed ones.
__global__ __launch_bounds__(256, 4) void k_fused(
    const __hip_bfloat16* __restrict__ xa, const float* __restrict__ om_w,
    const float* __restrict__ om_b, float* __restrict__ out)
{
    __shared__ __align__(16) uint4 uPool[1536];  // 24576 B: wL, then out_s[2]
    __shared__ float om_s[FT * 25];              // 6400 B

    int t  = threadIdx.x;
    int n  = blockIdx.y;
    int h  = blockIdx.z;        // group-half 0/1
    int l0 = blockIdx.x * FT;
    int h12 = 12 * h;

    ushort* wL = reinterpret_cast<ushort*>(uPool);

    // phase 1: pack om_w [48][256] -> wL (verified map, r15-verbatim)
    #pragma unroll 12
    for (int it = 0; it < 48; ++it) {
        int idx = it * 256 + t;
        int o   = idx >> 8;
        int c   = idx & 255;
        int nt  = o >> 4;
        int ks  = c >> 5;
        int qq  = (c & 31) >> 3;
        int j   = c & 7;
        int lane = (o & 15) | (qq << 4);
        wL[((ks * 3 + nt) * 64 + lane) * 8 + j] = f2bf(om_w[idx]);
    }
    __syncthreads();

    // phase 2: om[64][48] = xa_tile @ wL + om_b; predicate-store 24 cols -> om_s
    int lane = t & 63;
    int wv   = t >> 6;          // wave = mtile 0..3
    int col  = lane & 15;
    int q    = lane >> 4;
    const ushort* xp = reinterpret_cast<const ushort*>(xa);
    const short8v* A0 = reinterpret_cast<const short8v*>(
        xp + ((size_t)n * LL + l0 + wv * 16 + col) * CC + q * 8);
    const short8v* Bb = reinterpret_cast<const short8v*>(wL) + lane;

    floatx4 c0 = {0.f,0.f,0.f,0.f}, c1 = {0.f,0.f,0.f,0.f}, c2 = {0.f,0.f,0.f,0.f};
    #pragma unroll
    for (int ks = 0; ks < 8; ++ks) {
        short8v a = A0[ks * 4];
        c0 = __builtin_amdgcn_mfma_f32_16x16x32_bf16(a, Bb[(ks*3+0)*64], c0, 0, 0, 0);
        c1 = __builtin_amdgcn_mfma_f32_16x16x32_bf16(a, Bb[(ks*3+1)*64], c1, 0, 0, 0);
        c2 = __builtin_amdgcn_mfma_f32_16x16x32_bf16(a, Bb[(ks*3+2)*64], c2, 0, 0, 0);
    }
    float b0 = om_b[col];
    float b1 = om_b[16 + col];
    float b2 = om_b[32 + col];
    #pragma unroll
    for (int i = 0; i < 4; ++i) {
        int row = wv * 16 + q * 4 + i;
        float* os = om_s + row * 25;
        float vals[3] = {c0[i] + b0, c1[i] + b1, c2[i] + b2};
        int   gcs[3]  = {col, 16 + col, 32 + col};
        #pragma unroll
        for (int f = 0; f < 3; ++f) {
            int gc = gcs[f];
            if (gc >= h12 && gc < h12 + 12)               os[gc - h12] = vals[f];
            else if (gc >= 24 + h12 && gc < 36 + h12)     os[12 + gc - 24 - h12] = vals[f];
        }
    }
    __syncthreads();   // wL reads all done -> uPool becomes out_s[2]

    // phase 3: group-pair gather + mask aggregation (local groups 0..3)
    int cq = t & 3;        // channel oct within group
    int ps = t >> 2;       // position 0..63
    int c4 = t & 15;       // write phase: float4 column
    int rw = t >> 4;       // write phase: row 0..15
    size_t xb2 = (size_t)n * LL * CC;
    float* outs = reinterpret_cast<float*>(uPool);   // [2][GCC][68]
    float* ob0 = outs;
    float* ob1 = outs + (GCC * 68);
    int colw = ps ^ (cq << 3);   // swizzled store column

    #pragma unroll
    for (int gp = 0; gp < 4; gp += 2) {
        int g0 = 4 * h + gp;
        const __hip_bfloat16* xab0 = xa + xb2 + (size_t)(g0 + 0) * GCC + cq * 8;
        const __hip_bfloat16* xab1 = xa + xb2 + (size_t)(g0 + 1) * GCC + cq * 8;
        float acc0[8] = {0.f,0.f,0.f,0.f,0.f,0.f,0.f,0.f};
        float acc1[8] = {0.f,0.f,0.f,0.f,0.f,0.f,0.f,0.f};
        #pragma unroll
        for (int k = 0; k < KK; ++k) {
            float base = (float)(l0 + ps - 1 + k);
            // local group gp
            float off0  = om_s[ps * 25 + (gp + 0) * 3 + k];
            float msk0  = om_s[ps * 25 + 12 + (gp + 0) * 3 + k];
            float pA  = base + off0;
            float pA0 = floorf(pA);
            float wA1 = pA - pA0;
            int iA0 = (int)pA0;
            int iA1 = iA0 + 1;
            float aA0 = (iA0 >= 0 && iA0 < LL) ? msk0 * (1.f - wA1) : 0.f;
            float aA1 = (iA1 >= 0 && iA1 < LL) ? msk0 * wA1 : 0.f;
            iA0 = min(max(iA0, 0), LL - 1);
            iA1 = min(max(iA1, 0), LL - 1);
            // local group gp+1
            float off1  = om_s[ps * 25 + (gp + 1) * 3 + k];
            float msk1  = om_s[ps * 25 + 12 + (gp + 1) * 3 + k];
            float pB  = base + off1;
            float pB0 = floorf(pB);
            float wB1 = pB - pB0;
            int iB0 = (int)pB0;
            int iB1 = iB0 + 1;
            float aB0 = (iB0 >= 0 && iB0 < LL) ? msk1 * (1.f - wB1) : 0.f;
            float aB1 = (iB1 >= 0 && iB1 < LL) ? msk1 * wB1 : 0.f;
            iB0 = min(max(iB0, 0), LL - 1);
            iB1 = min(max(iB1, 0), LL - 1);

            uint4 rA0 = *reinterpret_cast<const uint4*>(xab0 + (size_t)iA0 * CC);
            uint4 rA1 = *reinterpret_cast<const uint4*>(xab0 + (size_t)iA1 * CC);
            uint4 rB0 = *reinterpret_cast<const uint4*>(xab1 + (size_t)iB0 * CC);
            uint4 rB1 = *reinterpret_cast<const uint4*>(xab1 + (size_t)iB1 * CC);
            uint uA0[4] = {rA0.x, rA0.y, rA0.z, rA0.w};
            uint uA1[4] = {rA1.x, rA1.y, rA1.z, rA1.w};
            uint uB0[4] = {rB0.x, rB0.y, rB0.z, rB0.w};
            uint uB1[4] = {rB1.x, rB1.y, rB1.z, rB1.w};
            #pragma unroll
            for (int d = 0; d < 4; ++d) {
                acc0[2*d]   = fmaf(aA0, __uint_as_float(uA0[d] << 16),
                              fmaf(aA1, __uint_as_float(uA1[d] << 16), acc0[2*d]));
                acc0[2*d+1] = fmaf(aA0, __uint_as_float(uA0[d] & 0xffff0000u),
                              fmaf(aA1, __uint_as_float(uA1[d] & 0xffff0000u), acc0[2*d+1]));
                acc1[2*d]   = fmaf(aB0, __uint_as_float(uB0[d] << 16),
                              fmaf(aB1, __uint_as_float(uB1[d] << 16), acc1[2*d]));
                acc1[2*d+1] = fmaf(aB0, __uint_as_float(uB0[d] & 0xffff0000u),
                              fmaf(aB1, __uint_as_float(uB1[d] & 0xffff0000u), acc1[2*d+1]));
            }
        }
        #pragma unroll
        for (int j = 0; j < 8; ++j) {
            int row = cq * 8 + j;
            ob0[row * 68 + colw] = acc0[j];
            ob1[row * 68 + colw] = acc1[j];
        }
        __syncthreads();

        float* op0 = out + ((size_t)n * CC + (size_t)(g0 + 0) * GCC) * LL + l0;
        float* op1 = op0 + (size_t)GCC * LL;
        #pragma unroll
        for (int rr = 0; rr < 2; ++rr) {
            int row = rw + rr * 16;
            int colr = (c4 * 4) ^ ((row >> 3) << 3);
            float4 v0 = *reinterpret_cast<const float4*>(&ob0[row * 68 + colr]);
            float4 v1 = *reinterpret_cast<const float4*>(&ob1[row * 68 + colr]);
            *reinterpret_cast<float4*>(op0 + (size_t)row * LL + c4 * 4) = v0;
            *reinterpret_cast<float4*>(op1 + (size_t)row * LL + c4 * 4) = v1;
        }
        if (gp == 0) __syncthreads();   // protect buffers before next pair's writes
    }
}

extern "C" void kernel_launch(void* const* d_in, const int* in_sizes, int n_in,
                              void* d_out, int out_size, void* d_ws, size_t ws_size,
                              hipStream_t stream) {
    const float* x    = (const float*)d_in[0];
    const float* ln_w = (const float*)d_in[1];
    const float* ln_b = (const float*)d_in[2];
    const float* om_w = (const float*)d_in[3];
    const float* om_b = (const float*)d_in[4];
    float* out = (float*)d_out;

    __hip_bfloat16* xa = (__hip_bfloat16*)((char*)d_ws + 49152); // 32 MB

    dim3 g1(LL / TL, NN);
    k_ln_gelu<<<g1, 256, 0, stream>>>(x, ln_w, ln_b, xa);

    dim3 g2(LL / FT, NN, 2);
    k_fused<<<g2, 256, 0, stream>>>(xa, om_w, om_b, out);
}

// Round 24
// 51.174 us; speedup vs baseline: 1.1227x; 1.1227x over previous
//
#include <hip/hip_runtime.h>
#include <hip/hip_bf16.h>
#include <math.h>

#define NN 8
#define CC 256
#define LL 8192
#define KK 3
#define GG 8
#define GCC 32
#define OMD 48  // 2*G*K
#define TL 32   // k1 positions per block
#define FT 64   // fused-kernel positions per block

typedef __attribute__((ext_vector_type(8))) short short8v;   // 8 bf16 (4 VGPR)
typedef __attribute__((ext_vector_type(4))) float floatx4;

__device__ inline ushort f2bf(float f) {
    uint u = __float_as_uint(f);
    u += 0x7fffu + ((u >> 16) & 1u);   // RNE
    return (ushort)(u >> 16);
}

// branch-free GELU (tanh form) via hardware exp: max |err vs exact| ~3e-3
__device__ inline float gelu_fast(float xn) {
    float u = xn * xn;
    float z = xn * (-1.5957691216f - 0.0713548162726f * u);
    return __fdividef(xn, 1.f + __expf(z));
}

// ---------------- kernel 1: LN + GELU -> xa bf16 [N,L,C] ----------------------
__global__ __launch_bounds__(256, 6) void k_ln_gelu(
    const float* __restrict__ x,
    const float* __restrict__ ln_w, const float* __restrict__ ln_b,
    __hip_bfloat16* __restrict__ xa)
{
    __shared__ __align__(16) float xs[128 * 33];   // 16896 B (= 1056 uint4)
    int n  = blockIdx.y;
    int l0 = blockIdx.x * TL;
    int t  = threadIdx.x;
    int p   = t >> 3;        // position 0..31
    int sub = t & 7;         // channel chunk 0..7
    int pp  = p ^ (sub << 2);

    const float* xbase = x + (size_t)n * CC * LL + l0;
    float r[32];

    float4 v[8];
    #pragma unroll
    for (int it = 0; it < 8; ++it) {
        int idx = it * 256 + t;
        int c   = idx >> 3;
        int l4  = idx & 7;
        v[it] = *reinterpret_cast<const float4*>(xbase + (size_t)c * LL + l4 * 4);
    }

    #pragma unroll
    for (int half = 0; half < 2; ++half) {
        if (half) __syncthreads();
        #pragma unroll
        for (int it = 0; it < 4; ++it) {
            int idx = (half * 4 + it) * 256 + t;
            int cl  = (idx >> 3) & 127;
            int l4  = idx & 7;
            int sw  = (cl >> 4) << 2;
            int b   = cl * 33;
            float4 vv = v[half * 4 + it];
            xs[b + ((4 * l4 + 0) ^ sw)] = vv.x;
            xs[b + ((4 * l4 + 1) ^ sw)] = vv.y;
            xs[b + ((4 * l4 + 2) ^ sw)] = vv.z;
            xs[b + ((4 * l4 + 3) ^ sw)] = vv.w;
        }
        __syncthreads();
        #pragma unroll
        for (int j = 0; j < 16; ++j)
            r[half * 16 + j] = xs[(sub * 16 + j) * 33 + pp];
    }

    float sum = 0.f, sq = 0.f;
    #pragma unroll
    for (int j = 0; j < 32; ++j) { sum += r[j]; sq = fmaf(r[j], r[j], sq); }
    #pragma unroll
    for (int m = 1; m <= 4; m <<= 1) {
        sum += __shfl_xor(sum, m);
        sq  += __shfl_xor(sq, m);
    }
    float mean = sum * (1.f / 256.f);
    float rstd = rsqrtf(sq * (1.f / 256.f) - mean * mean + 1e-6f);

    __syncthreads();   // all park-reads done; xs becomes the bf16 tile
    uint4* xb4 = reinterpret_cast<uint4*>(xs);   // [32 rows][33 uint4 pitch]

    #pragma unroll
    for (int half = 0; half < 2; ++half) {
        int cb = half * 128 + sub * 16;
        ushort pk[16];
        #pragma unroll
        for (int q = 0; q < 4; ++q) {
            float4 lw = *reinterpret_cast<const float4*>(ln_w + cb + 4 * q);
            float4 lb = *reinterpret_cast<const float4*>(ln_b + cb + 4 * q);
            float lww[4] = {lw.x, lw.y, lw.z, lw.w};
            float lbb[4] = {lb.x, lb.y, lb.z, lb.w};
            #pragma unroll
            for (int i = 0; i < 4; ++i) {
                int j = 4 * q + i;
                float xn = (r[half * 16 + j] - mean) * rstd * lww[i] + lbb[i];
                pk[j] = f2bf(gelu_fast(xn));
            }
        }
        #pragma unroll
        for (int q = 0; q < 2; ++q) {
            uint4 w4;
            w4.x = (uint)pk[8*q+0] | ((uint)pk[8*q+1] << 16);
            w4.y = (uint)pk[8*q+2] | ((uint)pk[8*q+3] << 16);
            w4.z = (uint)pk[8*q+4] | ((uint)pk[8*q+5] << 16);
            w4.w = (uint)pk[8*q+6] | ((uint)pk[8*q+7] << 16);
            xb4[p * 33 + (cb >> 3) + q] = w4;
        }
    }
    __syncthreads();

    // dense store: 1024 uint4, 4 per thread; each wave = 2 x 512 B contiguous
    #pragma unroll
    for (int it = 0; it < 4; ++it) {
        int idx = it * 256 + t;
        int row = idx >> 5;        // position 0..31
        int col = idx & 31;        // uint4 column
        uint4* dst = reinterpret_cast<uint4*>(xa + ((size_t)n * LL + l0 + row) * CC);
        dst[col] = xb4[row * 33 + col];
    }
}

// -------- kernel 2 (fused): om via MFMA -> LDS, then gather + aggregate -------
// (r22-identical: group pairs, out_s XOR-swizzled writes)
__global__ __launch_bounds__(256, 4) void k_fused(
    const __hip_bfloat16* __restrict__ xa, const float* __restrict__ om_w,
    const float* __restrict__ om_b, float* __restrict__ out)
{
    __shared__ __align__(16) uint4 uPool[1536];  // 24576 B: wL, then out_s[2]
    __shared__ float om_s[FT * 49];              // 12544 B

    int t  = threadIdx.x;
    int n  = blockIdx.y;
    int l0 = blockIdx.x * FT;

    ushort* wL = reinterpret_cast<ushort*>(uPool);

    // phase 1: pack om_w [48][256] -> wL (verified map, r15-verbatim)
    #pragma unroll 12
    for (int it = 0; it < 48; ++it) {
        int idx = it * 256 + t;
        int o   = idx >> 8;
        int c   = idx & 255;
        int nt  = o >> 4;
        int ks  = c >> 5;
        int qq  = (c & 31) >> 3;
        int j   = c & 7;
        int lane = (o & 15) | (qq << 4);
        wL[((ks * 3 + nt) * 64 + lane) * 8 + j] = f2bf(om_w[idx]);
    }
    __syncthreads();

    // phase 2: om[64][48] = xa_tile @ wL + om_b -> om_s (4 waves x 1 mtile)
    int lane = t & 63;
    int wv   = t >> 6;          // wave = mtile 0..3
    int col  = lane & 15;
    int q    = lane >> 4;
    const ushort* xp = reinterpret_cast<const ushort*>(xa);
    const short8v* A0 = reinterpret_cast<const short8v*>(
        xp + ((size_t)n * LL + l0 + wv * 16 + col) * CC + q * 8);
    const short8v* Bb = reinterpret_cast<const short8v*>(wL) + lane;

    floatx4 c0 = {0.f,0.f,0.f,0.f}, c1 = {0.f,0.f,0.f,0.f}, c2 = {0.f,0.f,0.f,0.f};
    #pragma unroll
    for (int ks = 0; ks < 8; ++ks) {
        short8v a = A0[ks * 4];
        c0 = __builtin_amdgcn_mfma_f32_16x16x32_bf16(a, Bb[(ks*3+0)*64], c0, 0, 0, 0);
        c1 = __builtin_amdgcn_mfma_f32_16x16x32_bf16(a, Bb[(ks*3+1)*64], c1, 0, 0, 0);
        c2 = __builtin_amdgcn_mfma_f32_16x16x32_bf16(a, Bb[(ks*3+2)*64], c2, 0, 0, 0);
    }
    float b0 = om_b[col];
    float b1 = om_b[16 + col];
    float b2 = om_b[32 + col];
    #pragma unroll
    for (int i = 0; i < 4; ++i) {
        int row = wv * 16 + q * 4 + i;
        om_s[row * 49 + col]      = c0[i] + b0;
        om_s[row * 49 + 16 + col] = c1[i] + b1;
        om_s[row * 49 + 32 + col] = c2[i] + b2;
    }
    __syncthreads();   // wL reads all done -> uPool becomes out_s[2]

    // phase 3: group-pair gather + mask aggregation
    int cq = t & 3;        // channel oct within group
    int ps = t >> 2;       // position 0..63
    int c4 = t & 15;       // write phase: float4 column
    int rw = t >> 4;       // write phase: row 0..15
    size_t xb2 = (size_t)n * LL * CC;
    float* outs = reinterpret_cast<float*>(uPool);   // [2][GCC][68]
    float* ob0 = outs;
    float* ob1 = outs + (GCC * 68);
    int colw = ps ^ (cq << 3);   // swizzled store column (row>>3 == cq)

    #pragma unroll
    for (int gp = 0; gp < GG; gp += 2) {
        const __hip_bfloat16* xab0 = xa + xb2 + (size_t)(gp + 0) * GCC + cq * 8;
        const __hip_bfloat16* xab1 = xa + xb2 + (size_t)(gp + 1) * GCC + cq * 8;
        float acc0[8] = {0.f,0.f,0.f,0.f,0.f,0.f,0.f,0.f};
        float acc1[8] = {0.f,0.f,0.f,0.f,0.f,0.f,0.f,0.f};
        #pragma unroll
        for (int k = 0; k < KK; ++k) {
            float base = (float)(l0 + ps - 1 + k);
            // group gp
            float off0  = om_s[ps * 49 + (gp + 0) * KK + k];
            float msk0  = om_s[ps * 49 + 24 + (gp + 0) * KK + k];
            float pA  = base + off0;
            float pA0 = floorf(pA);
            float wA1 = pA - pA0;
            int iA0 = (int)pA0;
            int iA1 = iA0 + 1;
            float aA0 = (iA0 >= 0 && iA0 < LL) ? msk0 * (1.f - wA1) : 0.f;
            float aA1 = (iA1 >= 0 && iA1 < LL) ? msk0 * wA1 : 0.f;
            iA0 = min(max(iA0, 0), LL - 1);
            iA1 = min(max(iA1, 0), LL - 1);
            // group gp+1
            float off1  = om_s[ps * 49 + (gp + 1) * KK + k];
            float msk1  = om_s[ps * 49 + 24 + (gp + 1) * KK + k];
            float pB  = base + off1;
            float pB0 = floorf(pB);
            float wB1 = pB - pB0;
            int iB0 = (int)pB0;
            int iB1 = iB0 + 1;
            float aB0 = (iB0 >= 0 && iB0 < LL) ? msk1 * (1.f - wB1) : 0.f;
            float aB1 = (iB1 >= 0 && iB1 < LL) ? msk1 * wB1 : 0.f;
            iB0 = min(max(iB0, 0), LL - 1);
            iB1 = min(max(iB1, 0), LL - 1);

            uint4 rA0 = *reinterpret_cast<const uint4*>(xab0 + (size_t)iA0 * CC);
            uint4 rA1 = *reinterpret_cast<const uint4*>(xab0 + (size_t)iA1 * CC);
            uint4 rB0 = *reinterpret_cast<const uint4*>(xab1 + (size_t)iB0 * CC);
            uint4 rB1 = *reinterpret_cast<const uint4*>(xab1 + (size_t)iB1 * CC);
            uint uA0[4] = {rA0.x, rA0.y, rA0.z, rA0.w};
            uint uA1[4] = {rA1.x, rA1.y, rA1.z, rA1.w};
            uint uB0[4] = {rB0.x, rB0.y, rB0.z, rB0.w};
            uint uB1[4] = {rB1.x, rB1.y, rB1.z, rB1.w};
            #pragma unroll
            for (int d = 0; d < 4; ++d) {
                acc0[2*d]   = fmaf(aA0, __uint_as_float(uA0[d] << 16),
                              fmaf(aA1, __uint_as_float(uA1[d] << 16), acc0[2*d]));
                acc0[2*d+1] = fmaf(aA0, __uint_as_float(uA0[d] & 0xffff0000u),
                              fmaf(aA1, __uint_as_float(uA1[d] & 0xffff0000u), acc0[2*d+1]));
                acc1[2*d]   = fmaf(aB0, __uint_as_float(uB0[d] << 16),
                              fmaf(aB1, __uint_as_float(uB1[d] << 16), acc1[2*d]));
                acc1[2*d+1] = fmaf(aB0, __uint_as_float(uB0[d] & 0xffff0000u),
                              fmaf(aB1, __uint_as_float(uB1[d] & 0xffff0000u), acc1[2*d+1]));
            }
        }
        #pragma unroll
        for (int j = 0; j < 8; ++j) {
            int row = cq * 8 + j;
            ob0[row * 68 + colw] = acc0[j];
            ob1[row * 68 + colw] = acc1[j];
        }
        __syncthreads();

        float* op0 = out + ((size_t)n * CC + (size_t)(gp + 0) * GCC) * LL + l0;
        float* op1 = op0 + (size_t)GCC * LL;
        #pragma unroll
        for (int rr = 0; rr < 2; ++rr) {
            int row = rw + rr * 16;
            int colr = (c4 * 4) ^ ((row >> 3) << 3);
            float4 v0 = *reinterpret_cast<const float4*>(&ob0[row * 68 + colr]);
            float4 v1 = *reinterpret_cast<const float4*>(&ob1[row * 68 + colr]);
            *reinterpret_cast<float4*>(op0 + (size_t)row * LL + c4 * 4) = v0;
            *reinterpret_cast<float4*>(op1 + (size_t)row * LL + c4 * 4) = v1;
        }
        if (gp < GG - 2) __syncthreads();   // protect buffers before next pair's writes
    }
}

extern "C" void kernel_launch(void* const* d_in, const int* in_sizes, int n_in,
                              void* d_out, int out_size, void* d_ws, size_t ws_size,
                              hipStream_t stream) {
    const float* x    = (const float*)d_in[0];
    const float* ln_w = (const float*)d_in[1];
    const float* ln_b = (const float*)d_in[2];
    const float* om_w = (const float*)d_in[3];
    const float* om_b = (const float*)d_in[4];
    float* out = (float*)d_out;

    __hip_bfloat16* xa = (__hip_bfloat16*)((char*)d_ws + 49152); // 32 MB

    dim3 g1(LL / TL, NN);
    k_ln_gelu<<<g1, 256, 0, stream>>>(x, ln_w, ln_b, xa);

    dim3 g2(LL / FT, NN);
    k_fused<<<g2, 256, 0, stream>>>(xa, om_w, om_b, out);
}